// Round 7
// baseline (213.881 us; speedup 1.0000x reference)
//
#include <hip/hip_runtime.h>

typedef short short8v __attribute__((ext_vector_type(8)));
typedef float f32x4 __attribute__((ext_vector_type(4)));
typedef unsigned short u16;
typedef unsigned int u32;

__device__ __forceinline__ u16 f2bf(float f) {
    u32 u = __float_as_uint(f);
    u += 0x7FFFu + ((u >> 16) & 1u);   // round-to-nearest-even
    return (u16)(u >> 16);
}
__device__ __forceinline__ float bf2f(u16 h) {
    return __uint_as_float(((u32)h) << 16);
}
// pack 2 f32 -> 2 bf16 in one u32 (lo = a, hi = b); RNE
__device__ __forceinline__ u32 cvtpk(float a, float b) {
    u32 d;
    asm("v_cvt_pk_bf16_f32 %0, %1, %2" : "=v"(d) : "v"(a), "v"(b));
    return d;
}
__device__ __forceinline__ short8v pack8(float4 a, float4 b) {
    union { u32 u[4]; short8v s; } r;
    r.u[0] = cvtpk(a.x, a.y); r.u[1] = cvtpk(a.z, a.w);
    r.u[2] = cvtpk(b.x, b.y); r.u[3] = cvtpk(b.z, b.w);
    return r.s;
}
// gelu(v) = 0.5 v (1 + tanh(u)) = v * sigmoid(2u), u = sqrt(2/pi)(v + 0.044715 v^3)
__device__ __forceinline__ float gelu_sig(float v) {
    float u = 0.7978845608028654f * fmaf(0.044715f * v, v * v, v);
    return v / (1.0f + __expf(-2.0f * u));
}

// ============ K0: W prep only ============
// w (f32 [4,512,512], [g][k][o]) -> wpk bf16 in B-fragment order.
// Fragment (g, c16, kb): lane l holds col c16*16+(l&15), k = kb*32+(l>>4)*8 .. +7.
__global__ __launch_bounds__(256) void k_prep(const float* __restrict__ w, u16* __restrict__ wpk) {
    int t = blockIdx.x * 256 + threadIdx.x;     // 0 .. 131071
    int lane = t & 63, kb = (t >> 6) & 15, c16 = (t >> 10) & 31, g = t >> 15;
    int col = c16 * 16 + (lane & 15);
    int k0 = kb * 32 + (lane >> 4) * 8;
    const float* src = w + (size_t)g * 262144 + (size_t)k0 * 512 + col;
    short8v s;
#pragma unroll
    for (int j = 0; j < 8; j++) s[j] = (short)f2bf(src[(size_t)j * 512]);
    *(short8v*)(wpk + (size_t)t * 8) = s;
}

// ============ K1: y = x @ W[grade] + bias (NO gelu), bf16 out ============
// M=32768, N=512, K=512. BM=BN=128, 4 waves (2x2), per-wave 64x64 out.
// A loaded straight from f32 x (2 dwordx4/frag) and packed in-reg via v_cvt_pk_bf16_f32.
// No LDS, no barriers; 2-deep register pipeline; XCD-chunked tile swizzle.
__global__ __launch_bounds__(256) void k_gemm(const float* __restrict__ x, const u16* __restrict__ wpk,
                                              const float* __restrict__ bias, u16* __restrict__ yb) {
    const int tid = threadIdx.x;
    const int w = tid >> 6, lane = tid & 63;
    // XCD-chunked bijective swizzle: each XCD gets 128 consecutive swz (32 mt x 4 nt)
    const int bid = blockIdx.x;
    const int swz = (bid & 7) * 128 + (bid >> 3);
    const int mt = swz >> 2, nt = swz & 3;          // 256 x 4 tiles of 128x128
    const int WE[8] = {0, 1, 1, 1, 2, 2, 2, 3};
    const int g = WE[mt >> 5];
    const int wr = w >> 1, wc = w & 1;

    // A: lane l of frag m holds row mt*128+wr*64+m*16+(l&15), k = kb*32+(l>>4)*8 ..+7 (f32)
    const float* Af = x + ((size_t)(mt * 128 + wr * 64 + (lane & 15))) * 512 + (lane >> 4) * 8;
    // B: packed fragments
    const char* Bb = (const char*)wpk + (size_t)(g * 32 + nt * 8 + wc * 4) * 16384 + lane * 16;

    f32x4 acc[4][4];
#pragma unroll
    for (int m = 0; m < 4; m++)
#pragma unroll
        for (int n = 0; n < 4; n++) acc[m][n] = (f32x4){0.f, 0.f, 0.f, 0.f};

    float4 fa0[4][2], fa1[4][2];
    short8v b0[4], b1[4];

#define LOADA(FA, KB) { \
    _Pragma("unroll") \
    for (int m = 0; m < 4; m++) { \
        const float4* p = (const float4*)(Af + (size_t)m * 8192 + (KB) * 32); \
        FA[m][0] = p[0]; FA[m][1] = p[1]; \
    } }
#define LOADB(BR, KB) { \
    _Pragma("unroll") \
    for (int n = 0; n < 4; n++) BR[n] = *(const short8v*)(Bb + (size_t)n * 16384 + (KB) * 1024); \
    }
#define MMA(FA, BR) { \
    short8v af[4]; \
    _Pragma("unroll") \
    for (int m = 0; m < 4; m++) af[m] = pack8(FA[m][0], FA[m][1]); \
    _Pragma("unroll") \
    for (int m = 0; m < 4; m++) \
        _Pragma("unroll") \
        for (int n = 0; n < 4; n++) \
            acc[m][n] = __builtin_amdgcn_mfma_f32_16x16x32_bf16(af[m], BR[n], acc[m][n], 0, 0, 0); \
    }

    LOADA(fa0, 0); LOADB(b0, 0);
#pragma unroll
    for (int kb = 0; kb < 14; kb += 2) {
        LOADA(fa1, kb + 1); LOADB(b1, kb + 1);
        MMA(fa0, b0);
        LOADA(fa0, kb + 2); LOADB(b0, kb + 2);
        MMA(fa1, b1);
    }
    LOADA(fa1, 15); LOADB(b1, 15);
    MMA(fa0, b0);
    MMA(fa1, b1);
#undef LOADA
#undef LOADB
#undef MMA

    const size_t row0 = (size_t)mt * 128 + wr * 64;
    const int colBase = nt * 128 + wc * 64;
#pragma unroll
    for (int n = 0; n < 4; n++) {
        int col = colBase + n * 16 + (lane & 15);
        float bv = bias[col];
#pragma unroll
        for (int m = 0; m < 4; m++) {
#pragma unroll
            for (int j = 0; j < 4; j++) {
                size_t row = row0 + m * 16 + (lane >> 4) * 4 + j;
                yb[row * 512 + col] = f2bf(acc[m][n][j] + bv);
            }
        }
    }
}

// ============ K2: gelu(y) + geometric product + grade RMS norm ============
#define TERM(i, j, k, s, p) o[ff][k] = fmaf(s * wp[ff][p], xv[ff][i] * yv[ff][j], o[ff][k]);
#define GP_ALL \
    TERM(0,0,0, 1.0f,0) TERM(0,1,1, 1.0f,1) TERM(0,2,2, 1.0f,1) TERM(0,3,3, 1.0f,1) \
    TERM(0,4,4, 1.0f,2) TERM(0,5,5, 1.0f,2) TERM(0,6,6, 1.0f,2) TERM(0,7,7, 1.0f,3) \
    TERM(1,0,1, 1.0f,4) TERM(1,1,0, 1.0f,5) TERM(1,2,4, 1.0f,6) TERM(1,3,5, 1.0f,6) \
    TERM(1,4,2, 1.0f,7) TERM(1,5,3, 1.0f,7) TERM(1,6,7, 1.0f,8) TERM(1,7,6, 1.0f,9) \
    TERM(2,0,2, 1.0f,4) TERM(2,1,4,-1.0f,6) TERM(2,2,0, 1.0f,5) TERM(2,3,6, 1.0f,6) \
    TERM(2,4,1,-1.0f,7) TERM(2,5,7,-1.0f,8) TERM(2,6,3, 1.0f,7) TERM(2,7,5,-1.0f,9) \
    TERM(3,0,3, 1.0f,4) TERM(3,1,5,-1.0f,6) TERM(3,2,6,-1.0f,6) TERM(3,3,0, 1.0f,5) \
    TERM(3,4,7, 1.0f,8) TERM(3,5,1,-1.0f,7) TERM(3,6,2,-1.0f,7) TERM(3,7,4, 1.0f,9) \
    TERM(4,0,4, 1.0f,10) TERM(4,1,2,-1.0f,11) TERM(4,2,1, 1.0f,11) TERM(4,3,7, 1.0f,12) \
    TERM(4,4,0,-1.0f,13) TERM(4,5,6,-1.0f,14) TERM(4,6,5, 1.0f,14) TERM(4,7,3,-1.0f,15) \
    TERM(5,0,5, 1.0f,10) TERM(5,1,3,-1.0f,11) TERM(5,2,7,-1.0f,12) TERM(5,3,1, 1.0f,11) \
    TERM(5,4,6, 1.0f,14) TERM(5,5,0,-1.0f,13) TERM(5,6,4,-1.0f,14) TERM(5,7,2, 1.0f,15) \
    TERM(6,0,6, 1.0f,10) TERM(6,1,7, 1.0f,12) TERM(6,2,3,-1.0f,11) TERM(6,3,2, 1.0f,11) \
    TERM(6,4,5,-1.0f,14) TERM(6,5,4, 1.0f,14) TERM(6,6,0,-1.0f,13) TERM(6,7,1,-1.0f,15) \
    TERM(7,0,7, 1.0f,16) TERM(7,1,6, 1.0f,17) TERM(7,2,5,-1.0f,17) TERM(7,3,4, 1.0f,17) \
    TERM(7,4,3,-1.0f,18) TERM(7,5,2, 1.0f,18) TERM(7,6,1,-1.0f,18) TERM(7,7,0,-1.0f,19)

__global__ __launch_bounds__(256) void k_gp(const float* __restrict__ x, const u16* __restrict__ yb,
                                            const float* __restrict__ gp, float* __restrict__ out) {
    const int b = blockIdx.x, tid = threadIdx.x;
    const int w = tid >> 6, lane = tid & 63;
    const int f0 = tid * 2;

    float xv[2][8], yv[2][8], wp[2][20], o[2][8];
#pragma unroll
    for (int i = 0; i < 8; i++) {
        float2 xf = *(const float2*)(x + ((size_t)i * 4096 + b) * 512 + f0);
        xv[0][i] = xf.x; xv[1][i] = xf.y;
        u32 uy = *(const u32*)(yb + ((size_t)i * 4096 + b) * 512 + f0);
        yv[0][i] = gelu_sig(bf2f((u16)(uy & 0xFFFF)));
        yv[1][i] = gelu_sig(bf2f((u16)(uy >> 16)));
    }
    // gp is [512][20] row-major; rows are 80 B -> 16B-aligned for every f
#pragma unroll
    for (int ff = 0; ff < 2; ++ff) {
        const float4* gv = (const float4*)(gp + (size_t)(f0 + ff) * 20);
#pragma unroll
        for (int q = 0; q < 5; ++q) {
            float4 v = gv[q];
            wp[ff][q * 4 + 0] = v.x; wp[ff][q * 4 + 1] = v.y;
            wp[ff][q * 4 + 2] = v.z; wp[ff][q * 4 + 3] = v.w;
        }
    }

    float ss[4] = {0.f, 0.f, 0.f, 0.f};
#pragma unroll
    for (int ff = 0; ff < 2; ++ff) {
#pragma unroll
        for (int k = 0; k < 8; k++) o[ff][k] = 0.f;
        GP_ALL
        ss[0] += o[ff][0] * o[ff][0];
        ss[1] += o[ff][1] * o[ff][1] + o[ff][2] * o[ff][2] + o[ff][3] * o[ff][3];
        ss[2] += o[ff][4] * o[ff][4] + o[ff][5] * o[ff][5] + o[ff][6] * o[ff][6];
        ss[3] += o[ff][7] * o[ff][7];
    }

#pragma unroll
    for (int g2 = 0; g2 < 4; g2++) {
        float v = ss[g2];
#pragma unroll
        for (int off = 32; off >= 1; off >>= 1) v += __shfl_xor(v, off);
        ss[g2] = v;
    }
    __shared__ float red[4][4];
    if (lane == 0) { red[w][0] = ss[0]; red[w][1] = ss[1]; red[w][2] = ss[2]; red[w][3] = ss[3]; }
    __syncthreads();
    float inv[4];
    const float cnt[4] = {512.f, 1536.f, 1536.f, 512.f};
#pragma unroll
    for (int g2 = 0; g2 < 4; g2++) {
        float tot = red[0][g2] + red[1][g2] + red[2][g2] + red[3][g2];
        inv[g2] = 1.0f / sqrtf(tot / cnt[g2] + 1e-6f);
    }
    const int GK[8] = {0, 1, 1, 1, 2, 2, 2, 3};
#pragma unroll
    for (int k = 0; k < 8; k++) {
        float2 st;
        st.x = o[0][k] * inv[GK[k]];
        st.y = o[1][k] * inv[GK[k]];
        *(float2*)(out + ((size_t)k * 4096 + b) * 512 + f0) = st;
    }
}

extern "C" void kernel_launch(void* const* d_in, const int* in_sizes, int n_in,
                              void* d_out, int out_size, void* d_ws, size_t ws_size,
                              hipStream_t stream) {
    const float* x  = (const float*)d_in[0];
    const float* lw = (const float*)d_in[1];
    const float* lb = (const float*)d_in[2];
    const float* gp = (const float*)d_in[3];
    float* out = (float*)d_out;
    char* ws = (char*)d_ws;
    u16* wpk = (u16*)ws;                        //  2,097,152 B (B fragments)
    u16* yb  = (u16*)(ws + 2097152);            // 33,554,432 B (pre-gelu y, bf16)

    hipLaunchKernelGGL(k_prep, dim3(512), dim3(256), 0, stream, lw, wpk);
    hipLaunchKernelGGL(k_gemm, dim3(1024), dim3(256), 0, stream, x, wpk, lb, yb);
    hipLaunchKernelGGL(k_gp, dim3(4096), dim3(256), 0, stream, x, yb, gp, out);
}

// Round 8
// 172.794 us; speedup vs baseline: 1.2378x; 1.2378x over previous
//
#include <hip/hip_runtime.h>

typedef short short8v __attribute__((ext_vector_type(8)));
typedef float f32x4 __attribute__((ext_vector_type(4)));
typedef unsigned short u16;
typedef unsigned int u32;

__device__ __forceinline__ u16 f2bf(float f) {
    u32 u = __float_as_uint(f);
    u += 0x7FFFu + ((u >> 16) & 1u);   // round-to-nearest-even
    return (u16)(u >> 16);
}
__device__ __forceinline__ float bf2f(u16 h) {
    return __uint_as_float(((u32)h) << 16);
}
// gelu(v) = 0.5 v (1 + tanh(u)) = v * sigmoid(2u), u = sqrt(2/pi)(v + 0.044715 v^3)
__device__ __forceinline__ float gelu_sig(float v) {
    float u = 0.7978845608028654f * fmaf(0.044715f * v, v * v, v);
    return v / (1.0f + __expf(-2.0f * u));
}

// ============ K0: prep ============
// Part 1 (blocks 0..8191): x (f32 [8,4096,512]) -> xpk, bf16 packed in MFMA A-fragment order.
//   Fragment (r16, kb): 64 lanes x 16B; lane l holds row r16*16+(l&15), k = kb*32+(l>>4)*8 .. +7.
// Part 2 (blocks 8192..8703): w (f32 [4,512,512], [g][k][o]) -> wpk, bf16 in B-fragment order.
__global__ __launch_bounds__(256) void k_prep(const float* __restrict__ x, u16* __restrict__ xpk,
                                              const float* __restrict__ w, u16* __restrict__ wpk) {
    const int bid = blockIdx.x, tid = threadIdx.x;
    if (bid < 8192) {
        int t = bid * 256 + tid;                    // 0 .. 2097151
        int lane = t & 63, kb = (t >> 6) & 15, r16 = t >> 10;
        int row = r16 * 16 + (lane & 15);
        int k0 = kb * 32 + (lane >> 4) * 8;
        const float4* src = (const float4*)(x + (size_t)row * 512 + k0);
        float4 a = src[0], c = src[1];
        short8v s;
        s[0] = (short)f2bf(a.x); s[1] = (short)f2bf(a.y); s[2] = (short)f2bf(a.z); s[3] = (short)f2bf(a.w);
        s[4] = (short)f2bf(c.x); s[5] = (short)f2bf(c.y); s[6] = (short)f2bf(c.z); s[7] = (short)f2bf(c.w);
        *(short8v*)(xpk + (size_t)t * 8) = s;
    } else {
        int t = (bid - 8192) * 256 + tid;           // 0 .. 131071
        int lane = t & 63, kb = (t >> 6) & 15, c16 = (t >> 10) & 31, g = t >> 15;
        int col = c16 * 16 + (lane & 15);
        int k0 = kb * 32 + (lane >> 4) * 8;
        const float* src = w + (size_t)g * 262144 + (size_t)k0 * 512 + col;
        short8v s;
#pragma unroll
        for (int j = 0; j < 8; j++) s[j] = (short)f2bf(src[(size_t)j * 512]);
        *(short8v*)(wpk + (size_t)t * 8) = s;
    }
}

// ============ K1: y = x @ W[grade] + bias (NO gelu), bf16 out ============
// M=32768, N=512, K=512. BM=BN=128, 4 waves (2x2), per-wave 64x64 out.
// No LDS, no barriers: packed fragments loaded global->reg (1KB coalesced/instr),
// 2-deep register pipeline; XCD-chunked swizzle groups the 4 nt of one mt per XCD.
__global__ __launch_bounds__(256) void k_gemm(const u16* __restrict__ xpk, const u16* __restrict__ wpk,
                                              const float* __restrict__ bias, u16* __restrict__ yb) {
    const int tid = threadIdx.x;
    const int w = tid >> 6, lane = tid & 63;
    // XCD-chunked bijective swizzle: 1024 blocks, chunk of 128 consecutive swz per XCD
    const int bid = blockIdx.x;
    const int swz = (bid & 7) * 128 + (bid >> 3);
    const int mt = swz >> 2, nt = swz & 3;          // 256 x 4 tiles of 128x128
    const int WE[8] = {0, 1, 1, 1, 2, 2, 2, 3};
    const int g = WE[mt >> 5];
    const int wr = w >> 1, wc = w & 1;
    const int loff = lane * 16;

    // byte base of fragment (idx, kb=0): idx*16KB; kb adds kb*1024
    const char* Ab = (const char*)xpk + (size_t)(mt * 8 + wr * 4) * 16384 + loff;
    const char* Bb = (const char*)wpk + (size_t)(g * 32 + nt * 8 + wc * 4) * 16384 + loff;

    f32x4 acc[4][4];
#pragma unroll
    for (int m = 0; m < 4; m++)
#pragma unroll
        for (int n = 0; n < 4; n++) acc[m][n] = (f32x4){0.f, 0.f, 0.f, 0.f};

    short8v a0[4], b0[4], a1[4], b1[4];

#define LOADF(AR, BR, KB) { \
    _Pragma("unroll") \
    for (int m = 0; m < 4; m++) AR[m] = *(const short8v*)(Ab + (size_t)m * 16384 + (KB) * 1024); \
    _Pragma("unroll") \
    for (int n = 0; n < 4; n++) BR[n] = *(const short8v*)(Bb + (size_t)n * 16384 + (KB) * 1024); \
    }
#define MM(AR, BR) { \
    _Pragma("unroll") \
    for (int m = 0; m < 4; m++) \
        _Pragma("unroll") \
        for (int n = 0; n < 4; n++) \
            acc[m][n] = __builtin_amdgcn_mfma_f32_16x16x32_bf16(AR[m], BR[n], acc[m][n], 0, 0, 0); \
    }

    LOADF(a0, b0, 0);
#pragma unroll
    for (int kb = 0; kb < 14; kb += 2) {
        LOADF(a1, b1, kb + 1);
        MM(a0, b0);
        LOADF(a0, b0, kb + 2);
        MM(a1, b1);
    }
    LOADF(a1, b1, 15);
    MM(a0, b0);
    MM(a1, b1);
#undef LOADF
#undef MM

    const size_t row0 = (size_t)mt * 128 + wr * 64;
    const int colBase = nt * 128 + wc * 64;
#pragma unroll
    for (int n = 0; n < 4; n++) {
        int col = colBase + n * 16 + (lane & 15);
        float bv = bias[col];
#pragma unroll
        for (int m = 0; m < 4; m++) {
#pragma unroll
            for (int j = 0; j < 4; j++) {
                size_t row = row0 + m * 16 + (lane >> 4) * 4 + j;
                yb[row * 512 + col] = f2bf(acc[m][n][j] + bv);
            }
        }
    }
}

// ============ K2: gelu(y) + geometric product + grade RMS norm ============
#define TERM(i, j, k, s, p) o[ff][k] = fmaf(s * wp[ff][p], xv[ff][i] * yv[ff][j], o[ff][k]);
#define GP_ALL \
    TERM(0,0,0, 1.0f,0) TERM(0,1,1, 1.0f,1) TERM(0,2,2, 1.0f,1) TERM(0,3,3, 1.0f,1) \
    TERM(0,4,4, 1.0f,2) TERM(0,5,5, 1.0f,2) TERM(0,6,6, 1.0f,2) TERM(0,7,7, 1.0f,3) \
    TERM(1,0,1, 1.0f,4) TERM(1,1,0, 1.0f,5) TERM(1,2,4, 1.0f,6) TERM(1,3,5, 1.0f,6) \
    TERM(1,4,2, 1.0f,7) TERM(1,5,3, 1.0f,7) TERM(1,6,7, 1.0f,8) TERM(1,7,6, 1.0f,9) \
    TERM(2,0,2, 1.0f,4) TERM(2,1,4,-1.0f,6) TERM(2,2,0, 1.0f,5) TERM(2,3,6, 1.0f,6) \
    TERM(2,4,1,-1.0f,7) TERM(2,5,7,-1.0f,8) TERM(2,6,3, 1.0f,7) TERM(2,7,5,-1.0f,9) \
    TERM(3,0,3, 1.0f,4) TERM(3,1,5,-1.0f,6) TERM(3,2,6,-1.0f,6) TERM(3,3,0, 1.0f,5) \
    TERM(3,4,7, 1.0f,8) TERM(3,5,1,-1.0f,7) TERM(3,6,2,-1.0f,7) TERM(3,7,4, 1.0f,9) \
    TERM(4,0,4, 1.0f,10) TERM(4,1,2,-1.0f,11) TERM(4,2,1, 1.0f,11) TERM(4,3,7, 1.0f,12) \
    TERM(4,4,0,-1.0f,13) TERM(4,5,6,-1.0f,14) TERM(4,6,5, 1.0f,14) TERM(4,7,3,-1.0f,15) \
    TERM(5,0,5, 1.0f,10) TERM(5,1,3,-1.0f,11) TERM(5,2,7,-1.0f,12) TERM(5,3,1, 1.0f,11) \
    TERM(5,4,6, 1.0f,14) TERM(5,5,0,-1.0f,13) TERM(5,6,4,-1.0f,14) TERM(5,7,2, 1.0f,15) \
    TERM(6,0,6, 1.0f,10) TERM(6,1,7, 1.0f,12) TERM(6,2,3,-1.0f,11) TERM(6,3,2, 1.0f,11) \
    TERM(6,4,5,-1.0f,14) TERM(6,5,4, 1.0f,14) TERM(6,6,0,-1.0f,13) TERM(6,7,1,-1.0f,15) \
    TERM(7,0,7, 1.0f,16) TERM(7,1,6, 1.0f,17) TERM(7,2,5,-1.0f,17) TERM(7,3,4, 1.0f,17) \
    TERM(7,4,3,-1.0f,18) TERM(7,5,2, 1.0f,18) TERM(7,6,1,-1.0f,18) TERM(7,7,0,-1.0f,19)

__global__ __launch_bounds__(256) void k_gp(const float* __restrict__ x, const u16* __restrict__ yb,
                                            const float* __restrict__ gp, float* __restrict__ out) {
    const int b = blockIdx.x, tid = threadIdx.x;
    const int w = tid >> 6, lane = tid & 63;
    const int f0 = tid * 2;

    float xv[2][8], yv[2][8], wp[2][20], o[2][8];
#pragma unroll
    for (int i = 0; i < 8; i++) {
        float2 xf = *(const float2*)(x + ((size_t)i * 4096 + b) * 512 + f0);
        xv[0][i] = xf.x; xv[1][i] = xf.y;
        u32 uy = *(const u32*)(yb + ((size_t)i * 4096 + b) * 512 + f0);
        yv[0][i] = gelu_sig(bf2f((u16)(uy & 0xFFFF)));
        yv[1][i] = gelu_sig(bf2f((u16)(uy >> 16)));
    }
    // gp is [512][20] row-major; rows are 80 B -> 16B-aligned for every f
#pragma unroll
    for (int ff = 0; ff < 2; ++ff) {
        const float4* gv = (const float4*)(gp + (size_t)(f0 + ff) * 20);
#pragma unroll
        for (int q = 0; q < 5; ++q) {
            float4 v = gv[q];
            wp[ff][q * 4 + 0] = v.x; wp[ff][q * 4 + 1] = v.y;
            wp[ff][q * 4 + 2] = v.z; wp[ff][q * 4 + 3] = v.w;
        }
    }

    float ss[4] = {0.f, 0.f, 0.f, 0.f};
#pragma unroll
    for (int ff = 0; ff < 2; ++ff) {
#pragma unroll
        for (int k = 0; k < 8; k++) o[ff][k] = 0.f;
        GP_ALL
        ss[0] += o[ff][0] * o[ff][0];
        ss[1] += o[ff][1] * o[ff][1] + o[ff][2] * o[ff][2] + o[ff][3] * o[ff][3];
        ss[2] += o[ff][4] * o[ff][4] + o[ff][5] * o[ff][5] + o[ff][6] * o[ff][6];
        ss[3] += o[ff][7] * o[ff][7];
    }

#pragma unroll
    for (int g2 = 0; g2 < 4; g2++) {
        float v = ss[g2];
#pragma unroll
        for (int off = 32; off >= 1; off >>= 1) v += __shfl_xor(v, off);
        ss[g2] = v;
    }
    __shared__ float red[4][4];
    if (lane == 0) { red[w][0] = ss[0]; red[w][1] = ss[1]; red[w][2] = ss[2]; red[w][3] = ss[3]; }
    __syncthreads();
    float inv[4];
    const float cnt[4] = {512.f, 1536.f, 1536.f, 512.f};
#pragma unroll
    for (int g2 = 0; g2 < 4; g2++) {
        float tot = red[0][g2] + red[1][g2] + red[2][g2] + red[3][g2];
        inv[g2] = 1.0f / sqrtf(tot / cnt[g2] + 1e-6f);
    }
    const int GK[8] = {0, 1, 1, 1, 2, 2, 2, 3};
#pragma unroll
    for (int k = 0; k < 8; k++) {
        float2 st;
        st.x = o[0][k] * inv[GK[k]];
        st.y = o[1][k] * inv[GK[k]];
        *(float2*)(out + ((size_t)k * 4096 + b) * 512 + f0) = st;
    }
}

extern "C" void kernel_launch(void* const* d_in, const int* in_sizes, int n_in,
                              void* d_out, int out_size, void* d_ws, size_t ws_size,
                              hipStream_t stream) {
    const float* x  = (const float*)d_in[0];
    const float* lw = (const float*)d_in[1];
    const float* lb = (const float*)d_in[2];
    const float* gp = (const float*)d_in[3];
    float* out = (float*)d_out;
    char* ws = (char*)d_ws;
    u16* xpk = (u16*)ws;                        // 33,554,432 B (A fragments)
    u16* wpk = (u16*)(ws + 33554432);           //  2,097,152 B (B fragments)
    u16* yb  = (u16*)(ws + 35651584);           // 33,554,432 B (pre-gelu y, bf16)

    hipLaunchKernelGGL(k_prep, dim3(8704), dim3(256), 0, stream, x, xpk, lw, wpk);
    hipLaunchKernelGGL(k_gemm, dim3(1024), dim3(256), 0, stream, xpk, wpk, lb, yb);
    hipLaunchKernelGGL(k_gp, dim3(4096), dim3(256), 0, stream, x, yb, gp, out);
}